// Round 4
// baseline (42.488 us; speedup 1.0000x reference)
//
#include <hip/hip_runtime.h>
#include <hip/hip_bf16.h>

#define M 256
#define NOUT 1024
#define KTOT 16384
#define RANK 16
#define NKC 32          // split-K factor (grid.y)
#define KCHUNK 512      // K per block = KTOT/NKC
#define BKC 64          // K per LDS stage (one chunk)
#define BN 64           // cols per block = 4 waves * 16
#define NTILE 16        // NOUT/BN

typedef __attribute__((ext_vector_type(8))) short bf16x8_t;
typedef __attribute__((ext_vector_type(4))) float f32x4_t;
typedef __attribute__((ext_vector_type(8))) unsigned short u16x8_t;

static __device__ __forceinline__ unsigned short f2bf(float f) {
  unsigned u = __builtin_bit_cast(unsigned, f);
  u += 0x7FFFu + ((u >> 16) & 1u);   // round-to-nearest-even
  return (unsigned short)(u >> 16);
}
static __device__ __forceinline__ float bf2f(unsigned short h) {
  unsigned u = ((unsigned)h) << 16;
  return __builtin_bit_cast(float, u);
}

// X stored chunk-blocked + bank-swizzled:
//   element (b, k):  chunk = k>>6, u = (k&63)>>3, el = k&7
//   pos = (chunk*256 + b)*64 + ((u ^ (b&7)) * 8) + el        (bf16)
// Linear global_load_lds of a chunk then yields LDS rows of 128 B whose 16B
// slots are XOR-swizzled by (row&7) -> conflict-free ds_read_b128 fragments.
__global__ __launch_bounds__(256) void build_x_kernel(
    const float* __restrict__ input, const float* __restrict__ coef,
    unsigned short* __restrict__ X)
{
  int idx = blockIdx.x * 256 + threadIdx.x;   // idx = b*1024 + i
  int b = idx >> 10, i = idx & 1023;
  float in = input[idx];
  const float* c = coef + b * RANK;
  u16x8_t lo, hi;
  #pragma unroll
  for (int r = 0; r < 8; ++r) lo[r] = f2bf(in * c[r]);
  #pragma unroll
  for (int r = 0; r < 8; ++r) hi[r] = f2bf(in * c[8 + r]);
  int chunk = i >> 2;            // (i*16) >> 6
  int u0 = (i & 3) * 2;          // first 16B slot index within the row
  size_t base = ((size_t)chunk * 256 + b) * 64;
  *(u16x8_t*)(X + base + (size_t)((u0    ) ^ (b & 7)) * 8) = lo;
  *(u16x8_t*)(X + base + (size_t)((u0 + 1) ^ (b & 7)) * 8) = hi;
}

// GEMM: part[kc][b][o] (bf16) = sum_{k in chunk kc} X[b][k] * W[o][k]
// BM=256 (all M), BN=64: wave w owns cols [o0+w*16, +16). 512 blocks, 2/CU.
// W loads go DIRECTLY global->reg in the MFMA B-fragment layout, converted
// fp32->bf16 in-register; 3 named register sets = 2-region prefetch depth.
// A (X) double-buffered in LDS via global_load_lds. Synchronization is
// counted-vmcnt (T3/T4): s_waitcnt vmcnt(4) + raw s_barrier -- the previous
// STAGE (8 loads, one region older) is guaranteed landed by in-order VMEM
// return, while this region's 4 W-loads stay in flight. Never vmcnt(0) in
// the main loop. Issue order pinned with sched_barrier(0).
__global__ __launch_bounds__(256, 2) void gemm_kernel(
    const unsigned short* __restrict__ X, const float* __restrict__ W,
    unsigned short* __restrict__ part)
{
  __shared__ unsigned short As0[256 * 64];   // 32 KB
  __shared__ unsigned short As1[256 * 64];   // 32 KB

  const int tid = threadIdx.x;
  const int wid = tid >> 6, lane = tid & 63;
  const int lr = lane & 15, lg = lane >> 4;
  const int kc = blockIdx.y;
  const int o0 = blockIdx.x * BN + wid * 16;   // this wave's 16-col base
  const int ch0 = kc * (KCHUNK / BKC);         // global 64-k chunk base
  const int kb0 = kc * KCHUNK;

  f32x4_t acc[16];
  #pragma unroll
  for (int a = 0; a < 16; ++a) acc[a] = (f32x4_t)(0.0f);

  const float* wrow = W + (size_t)(o0 + lr) * KTOT + lg * 8;

  float4 bqA00, bqA01, bqA10, bqA11;
  float4 bqB00, bqB01, bqB10, bqB11;
  float4 bqC00, bqC01, bqC10, bqC11;

  #define SB __builtin_amdgcn_sched_barrier(0);

  #define STAGE(cch, ASBUF)                                                   \
    {                                                                         \
      const unsigned short* srcb = X + (size_t)(ch0 + (cch)) * 16384;         \
      _Pragma("unroll")                                                       \
      for (int j = 0; j < 8; ++j) {                                           \
        __builtin_amdgcn_global_load_lds(                                     \
            (const __attribute__((address_space(1))) unsigned int*)           \
                (srcb + (size_t)(j * 256 + tid) * 8),                         \
            (__attribute__((address_space(3))) unsigned int*)                 \
                (&ASBUF[(j * 256 + tid) * 8]),                                \
            16, 0, 0);                                                        \
      }                                                                       \
    }

  #define LOADB(S, cch)                                                      \
    {                                                                        \
      int ko = kb0 + (cch) * BKC;                                            \
      bq##S##00 = *(const float4*)(wrow + ko);                               \
      bq##S##01 = *(const float4*)(wrow + ko + 4);                           \
      bq##S##10 = *(const float4*)(wrow + ko + 32);                          \
      bq##S##11 = *(const float4*)(wrow + ko + 36);                          \
    }

  #define COMPIT(S, IT, ASBUF)                                               \
    {                                                                        \
      bf16x8_t bf;                                                           \
      _Pragma("unroll")                                                      \
      for (int e = 0; e < 4; ++e) {                                          \
        bf[e]     = (short)f2bf(bq##S##IT##0[e]);                            \
        bf[e + 4] = (short)f2bf(bq##S##IT##1[e]);                            \
      }                                                                      \
      __builtin_amdgcn_s_setprio(1);                                         \
      _Pragma("unroll")                                                      \
      for (int fm = 0; fm < 16; ++fm) {                                      \
        int row = fm * 16 + lr;                                              \
        int slot = ((IT) * 4 + lg) ^ (row & 7);                              \
        bf16x8_t av = *(const bf16x8_t*)&ASBUF[row * 64 + slot * 8];         \
        acc[fm] = __builtin_amdgcn_mfma_f32_16x16x32_bf16(                   \
            av, bf, acc[fm], 0, 0, 0);                                       \
      }                                                                      \
      __builtin_amdgcn_s_setprio(0);                                         \
    }

  #define COMPUTE(S, ASBUF) COMPIT(S, 0, ASBUF) COMPIT(S, 1, ASBUF)

  // counted-vmcnt barrier: previous STAGE (8 loads, issued one region ago)
  // must land; this region's 4 newest W-loads stay in flight.
  #define SYNC4                                                              \
    asm volatile("s_waitcnt vmcnt(4) lgkmcnt(0)" ::: "memory"); SB           \
    __builtin_amdgcn_s_barrier(); SB

  #define SYNC0                                                              \
    asm volatile("s_waitcnt vmcnt(0) lgkmcnt(0)" ::: "memory"); SB           \
    __builtin_amdgcn_s_barrier(); SB

  // ---- prologue: stage chunk 0, prefetch W sets A,B; wait only STAGE(0) ----
  STAGE(0, As0) SB
  LOADB(A, 0) SB
  LOADB(B, 1) SB
  asm volatile("s_waitcnt vmcnt(8)" ::: "memory"); SB
  __builtin_amdgcn_s_barrier(); SB

  // ---- straight-line regions; chunk c: set c%3, buffer As[c&1] ----
  STAGE(1, As1) SB LOADB(C, 2) SB COMPUTE(A, As0) SYNC4
  STAGE(2, As0) SB LOADB(A, 3) SB COMPUTE(B, As1) SYNC4
  STAGE(3, As1) SB LOADB(B, 4) SB COMPUTE(C, As0) SYNC4
  STAGE(4, As0) SB LOADB(C, 5) SB COMPUTE(A, As1) SYNC4
  STAGE(5, As1) SB LOADB(A, 6) SB COMPUTE(B, As0) SYNC4
  STAGE(6, As0) SB LOADB(B, 7) SB COMPUTE(C, As1) SYNC4
  STAGE(7, As1) SB COMPUTE(A, As0) SYNC0
  COMPUTE(B, As1)

  // ---- epilogue: C/D layout col=lane&15, row=(lane>>4)*4+j ----
  unsigned short* p = part + (size_t)kc * (M * NOUT);
  #pragma unroll
  for (int fm = 0; fm < 16; ++fm) {
    #pragma unroll
    for (int j = 0; j < 4; ++j) {
      int row = fm * 16 + lg * 4 + j;
      int col = o0 + lr;
      p[(size_t)row * NOUT + col] = f2bf(acc[fm][j]);
    }
  }
  #undef STAGE
  #undef LOADB
  #undef COMPIT
  #undef COMPUTE
  #undef SYNC4
  #undef SYNC0
  #undef SB
}

// out[b][o] = sum_kc bf2f(part[kc][b][o]) + sum_r bias[o][r]*coef[b][r]
__global__ __launch_bounds__(256) void reduce_bias_kernel(
    const unsigned short* __restrict__ part, const float* __restrict__ bias,
    const float* __restrict__ coef, float* __restrict__ out)
{
  int t = blockIdx.x * 256 + threadIdx.x;
  int idx8 = t * 8;                       // 8 consecutive outputs, same b
  int b = idx8 >> 10, o = idx8 & 1023;

  float s[8];
  #pragma unroll
  for (int j = 0; j < 8; ++j) s[j] = 0.f;

  #pragma unroll
  for (int c = 0; c < NKC; ++c) {
    u16x8_t v = *(const u16x8_t*)(part + (size_t)c * (M * NOUT) + idx8);
    #pragma unroll
    for (int j = 0; j < 8; ++j) s[j] += bf2f(v[j]);
  }

  const f32x4_t* cr = (const f32x4_t*)(coef + (size_t)b * RANK);
  f32x4_t c0 = cr[0], c1 = cr[1], c2 = cr[2], c3 = cr[3];
  #pragma unroll
  for (int j = 0; j < 8; ++j) {
    const f32x4_t* br = (const f32x4_t*)(bias + (size_t)(o + j) * RANK);
    f32x4_t b0 = br[0], b1 = br[1], b2 = br[2], b3 = br[3];
    float bb = 0.f;
    #pragma unroll
    for (int e = 0; e < 4; ++e)
      bb += b0[e] * c0[e] + b1[e] * c1[e] + b2[e] * c2[e] + b3[e] * c3[e];
    s[j] += bb;
  }
  float4* dst = (float4*)(out + idx8);
  dst[0] = make_float4(s[0], s[1], s[2], s[3]);
  dst[1] = make_float4(s[4], s[5], s[6], s[7]);
}

extern "C" void kernel_launch(void* const* d_in, const int* in_sizes, int n_in,
                              void* d_out, int out_size, void* d_ws, size_t ws_size,
                              hipStream_t stream) {
  const float* input = (const float*)d_in[0];   // (256, 1024)
  const float* coef  = (const float*)d_in[1];   // (256, 16)
  const float* W     = (const float*)d_in[2];   // (1024, 1024, 16) -> (1024, 16384)
  const float* bias  = (const float*)d_in[3];   // (1024, 16)
  float* out = (float*)d_out;                   // (256, 1024)

  unsigned short* X    = (unsigned short*)d_ws;                               // 8 MiB bf16
  unsigned short* part = (unsigned short*)((char*)d_ws + (size_t)M * KTOT * 2); // 16 MiB bf16

  build_x_kernel<<<(M * 1024) / 256, 256, 0, stream>>>(input, coef, X);
  gemm_kernel<<<dim3(NTILE, NKC), 256, 0, stream>>>(X, W, part);
  reduce_bias_kernel<<<(M * NOUT) / (256 * 8), 256, 0, stream>>>(part, bias, coef, out);
}